// Round 6
// baseline (412.404 us; speedup 1.0000x reference)
//
#include <hip/hip_runtime.h>

#define LL 256   // sequence length
#define EE 64    // embed dim
#define HH 64    // hidden dim
#define GG 256   // 4*H gates
#define VV 6000  // vocab
#define NSEQ 16  // sequences per block (full MFMA tile, no waste)
#define ROWP 72  // padded LDS row stride in bf16 elems (144 B, 16B-aligned)
#define VBLK 375 // phase-1 blocks per direction (6000/16)

typedef __bf16 bf16_t;
typedef bf16_t bf16x8 __attribute__((ext_vector_type(8)));
typedef float  f32x4  __attribute__((ext_vector_type(4)));

union BfPack {
    unsigned short u[8];
    bf16x8 v;
};

__device__ __forceinline__ unsigned short f2bf(float f) {
    return __builtin_bit_cast(unsigned short, (__bf16)f);
}

#define LOG2E 1.44269504088896340736f

// exp2+rcp activations (R1: removed IEEE div sequences). Inf-safe both ends.
__device__ __forceinline__ float sigm(float x) {
    float e = __builtin_amdgcn_exp2f(-LOG2E * x);          // e^{-x}
    return __builtin_amdgcn_rcpf(1.0f + e);
}
__device__ __forceinline__ float tanh_fast(float x) {
    float e = __builtin_amdgcn_exp2f((2.0f * LOG2E) * x);  // e^{2x}
    return 1.0f - 2.0f * __builtin_amdgcn_rcpf(e + 1.0f);
}

// lgkm-only barrier (R0->R1: 567->415 us): cross-wave deps are LDS-only;
// out-stores and pre-gathers stay in flight across it (vmcnt untouched).
#define LGKM_BARRIER() asm volatile("s_waitcnt lgkmcnt(0)\n\ts_barrier" ::: "memory")

// ---------------- phase 1: embedPre[dir][v][swz(g)] = bf16(embed@Wk + b) ----
// x_t @ Wk == (embed @ Wk)[id] : the whole input projection is a table.
// bf16 table (R5: FETCH 375->138 MB). Swizzle: pos = ((g>>4)&3)*64+(g&15)*4+
// (g>>6): phase-2 lane (w0,quad,l15) reads its 4 gate values per seq-row as
// ONE dwordx2 at elem [id*256 + w0*64 + l15*4].
__global__ __launch_bounds__(256)
void embed_pre_kernel(const float* __restrict__ embed,
                      const float* __restrict__ Wk_f, const float* __restrict__ b_f,
                      const float* __restrict__ Wk_b, const float* __restrict__ b_b,
                      unsigned short* __restrict__ pre)
{
    const int bid = blockIdx.x;
    const int dir = bid / VBLK;
    const int v0  = (bid % VBLK) * 16;
    const float* Wk = dir ? Wk_b : Wk_f;
    const float* bv = dir ? b_b  : b_f;
    unsigned short* dst = pre + (size_t)dir * VV * GG;

    const int tid = threadIdx.x;
    const int r   = tid >> 4;    // v-row 0..15
    const int cg  = tid & 15;    // col residue; thread owns g = k*16+cg

    __shared__ float sW[16][GG];   // 16 KB per E-chunk
    __shared__ float sE[16][17];   // 16 rows x 16 e, padded

    float acc[16];
    #pragma unroll
    for (int k = 0; k < 16; ++k) acc[k] = 0.f;

    for (int ec = 0; ec < 4; ++ec) {
        {   // stage Wk rows ec*16..+15 (coalesced float4) + embed chunk
            int er = tid >> 4;
            int c0 = (tid & 15) * 16;
            const float* src = &Wk[(size_t)(ec * 16 + er) * GG + c0];
            *(float4*)&sW[er][c0 + 0]  = *(const float4*)(src + 0);
            *(float4*)&sW[er][c0 + 4]  = *(const float4*)(src + 4);
            *(float4*)&sW[er][c0 + 8]  = *(const float4*)(src + 8);
            *(float4*)&sW[er][c0 + 12] = *(const float4*)(src + 12);
            sE[er][tid & 15] = embed[(size_t)(v0 + er) * EE + ec * 16 + (tid & 15)];
        }
        __syncthreads();
        #pragma unroll
        for (int e = 0; e < 16; ++e) {
            float xe = sE[r][e];
            #pragma unroll
            for (int k = 0; k < 16; ++k)
                acc[k] += xe * sW[e][k * 16 + cg];   // 16 consecutive banks, CF
        }
        __syncthreads();
    }
    #pragma unroll
    for (int a = 0; a < 4; ++a) {
        ushort4 pk;
        pk.x = f2bf(acc[a]      + bv[(a)      * 16 + cg]);
        pk.y = f2bf(acc[a + 4]  + bv[(a + 4)  * 16 + cg]);
        pk.z = f2bf(acc[a + 8]  + bv[(a + 8)  * 16 + cg]);
        pk.w = f2bf(acc[a + 12] + bv[(a + 12) * 16 + cg]);
        *(ushort4*)&dst[(size_t)(v0 + r) * GG + a * 64 + cg * 4] = pk;
    }
}

// ---------------- phase 2: recurrence, wave-specialized ---------------------
// 512 threads = 8 waves; pair (w0, w0+4) owns gate cols j = w0*16 + l15.
// Role 0 (waves 0-3), phase A: ds_read h, unpack P (depth-2 ping-pong
// gathers), 8 MFMAs, write rows-2,3 acc partials to LDS planes (stride-1,
// conflict-free). BAR1. Phase B: role 0 gate-maths rows 0,1 from registers;
// role 1 reads its 8 partial f32 and gate-maths rows 2,3. BAR2. Trans work
// per wave halves (40 -> 20 ops); 2 waves/SIMD overlap A-latency with
// B-issue (R5: 1 wave/SIMD, 52% VALUBusy, 48% unfillable stall).
__global__ __launch_bounds__(512, 2)
void bilstm_mfma(const int* __restrict__ ids,
                 const float* __restrict__ Wr_f, const float* __restrict__ Wr_b,
                 const unsigned short* __restrict__ pre,
                 float* __restrict__ out)
{
    const int dir = blockIdx.x >> 7;    // 0 fwd, 1 bwd
    const int grp = blockIdx.x & 127;
    const int n0  = grp * NSEQ;
    const int tid  = threadIdx.x;
    const int w    = tid >> 6;          // 0..7
    const int w0   = w & 3;             // col-group (pair id)
    const int role = w >> 2;            // 0: MFMA + rows 0,1; 1: rows 2,3
    const int lane = tid & 63;
    const int l15  = lane & 15;
    const int quad = lane >> 4;
    const int j    = w0 * 16 + l15;     // gate sub-index in [0,64)

    const float* Wr = dir ? Wr_b : Wr_f;
    const unsigned short* preT = pre + (size_t)dir * VV * GG;
    const int coff = w0 * 64 + l15 * 4; // lane's fixed swizzled elem offset

    __shared__ __align__(16) short s_h[2][NSEQ][ROWP];  // 4.5 KB
    __shared__ int s_ids[NSEQ][LL + 1];                 // 16.4 KB
    __shared__ float s_xacc[8][256];                    // 8 KB: [tt*2+rr][w0*64+lane]

    // stage ids (coalesced, all 512 threads)
    for (int p = tid; p < NSEQ * LL; p += 512) {
        int m = p >> 8, t = p & 255;
        s_ids[m][t] = ids[(size_t)(n0 + m) * LL + t];
    }
    // zero both h buffers (h0 = 0)
    for (int p = tid; p < 2 * NSEQ * ROWP; p += 512)
        (&s_h[0][0][0])[p] = 0;

    __syncthreads();

    // Role-0 state: Wr B-fragments (K=64) + depth-2 ping-pong P buffers
    bf16x8 bfrag[4][2];
    uint2 PA[4], PB[4];
    if (role == 0) {
        #pragma unroll
        for (int tt = 0; tt < 4; ++tt) {
            int g = tt * 64 + j;
            #pragma unroll
            for (int kc = 0; kc < 2; ++kc) {
                BfPack pk;
                #pragma unroll
                for (int e = 0; e < 8; ++e) {
                    int kg = kc * 32 + quad * 8 + e;
                    pk.u[e] = f2bf(Wr[(size_t)kg * GG + g]);
                }
                bfrag[tt][kc] = pk.v;
            }
        }
        int t0 = dir ? (LL - 1) : 0;
        int t1 = dir ? (LL - 2) : 1;
        #pragma unroll
        for (int r = 0; r < 4; ++r) {
            PA[r] = *(const uint2*)&preT[(size_t)s_ids[quad * 4 + r][t0] * GG + coff];
            PB[r] = *(const uint2*)&preT[(size_t)s_ids[quad * 4 + r][t1] * GG + coff];
        }
    }

    float c[2] = {0.f, 0.f};            // cell state: rows quad*4 + role*2 + rr
    const int rowb = quad * 4 + role * 2;

    // strength-reduced out pointers for this wave's 2 rows
    const int tstep = dir ? -(2 * HH) : (2 * HH);
    float* optr[2];
    {
        const int t0 = dir ? (LL - 1) : 0;
        #pragma unroll
        for (int rr = 0; rr < 2; ++rr)
            optr[rr] = out + ((size_t)(n0 + rowb + rr) * LL + t0) * (2 * HH) + dir * HH + j;
    }

    auto do_step = [&](int ts, uint2 (&P)[4]) {
        const int rb = ts & 1, wb = (ts + 1) & 1;

        f32x4 acc[4];
        if (role == 0) {
            // h A-fragments: lane reads A[m=l15][k=quad*8..+7] (ds_read_b128)
            bf16x8 ah0 = *(const bf16x8*)&s_h[rb][l15][quad * 8];
            bf16x8 ah1 = *(const bf16x8*)&s_h[rb][l15][32 + quad * 8];

            // consume P (loaded 2 steps ago): bf16->f32 + free 4x4 transpose
            f32x4 cIn[4];
            #pragma unroll
            for (int r = 0; r < 4; ++r) {
                cIn[0][r] = __uint_as_float(P[r].x << 16);
                cIn[1][r] = __uint_as_float(P[r].x & 0xffff0000u);
                cIn[2][r] = __uint_as_float(P[r].y << 16);
                cIn[3][r] = __uint_as_float(P[r].y & 0xffff0000u);
            }
            // branchless refill for ts+2 (clamped tail)
            {
                int tn = dir ? (LL - 3 - ts) : (ts + 2);
                tn = tn < 0 ? 0 : (tn > LL - 1 ? LL - 1 : tn);
                #pragma unroll
                for (int r = 0; r < 4; ++r)
                    P[r] = *(const uint2*)&preT[(size_t)s_ids[quad * 4 + r][tn] * GG + coff];
            }
            // z = pre-seed + h@Wr : 4 independent 2-deep MFMA chains
            #pragma unroll
            for (int tt = 0; tt < 4; ++tt) {
                f32x4 a = __builtin_amdgcn_mfma_f32_16x16x32_bf16(ah0, bfrag[tt][0], cIn[tt], 0, 0, 0);
                acc[tt]  = __builtin_amdgcn_mfma_f32_16x16x32_bf16(ah1, bfrag[tt][1], a, 0, 0, 0);
            }
            // hand rows 2,3 to the partner wave (stride-1 planes, CF)
            #pragma unroll
            for (int tt = 0; tt < 4; ++tt) {
                s_xacc[tt * 2 + 0][w0 * 64 + lane] = acc[tt][2];
                s_xacc[tt * 2 + 1][w0 * 64 + lane] = acc[tt][3];
            }
        }
        LGKM_BARRIER();   // BAR1: acc partials visible to role 1

        // fetch this wave's 2 rows of z (wave-uniform branch, no lane waste)
        float z[4][2];
        if (role == 0) {
            #pragma unroll
            for (int tt = 0; tt < 4; ++tt) {
                z[tt][0] = acc[tt][0];
                z[tt][1] = acc[tt][1];
            }
        } else {
            #pragma unroll
            for (int tt = 0; tt < 4; ++tt) {
                z[tt][0] = s_xacc[tt * 2 + 0][w0 * 64 + lane];
                z[tt][1] = s_xacc[tt * 2 + 1][w0 * 64 + lane];
            }
        }

        // gate math: 2 rows per wave (trans halved vs R5)
        #pragma unroll
        for (int rr = 0; rr < 2; ++rr) {
            float ig = sigm(z[0][rr]);
            float fg = sigm(z[1][rr]);
            float gg = tanh_fast(z[2][rr]);
            float og = sigm(z[3][rr]);
            c[rr] = fg * c[rr] + ig * gg;
            float hh = og * tanh_fast(c[rr]);
            *optr[rr] = hh;                       // plain store: fast L2 ack
            optr[rr] += tstep;
            s_h[wb][rowb + rr][j] = (short)f2bf(hh);
        }
        LGKM_BARRIER();   // BAR2: h visible; also orders s_xacc reads before
                          // next step's overwrite (single-buffer safe)
    };

    for (int ts = 0; ts < LL; ts += 2) {
        do_step(ts,     PA);
        do_step(ts + 1, PB);
    }
}

extern "C" void kernel_launch(void* const* d_in, const int* in_sizes, int n_in,
                              void* d_out, int out_size, void* d_ws, size_t ws_size,
                              hipStream_t stream) {
    const int*   ids   = (const int*)d_in[0];
    const float* embed = (const float*)d_in[1];
    const float* Wk_f  = (const float*)d_in[2];
    const float* Wr_f  = (const float*)d_in[3];
    const float* b_f   = (const float*)d_in[4];
    const float* Wk_b  = (const float*)d_in[5];
    const float* Wr_b  = (const float*)d_in[6];
    const float* b_b   = (const float*)d_in[7];
    float* out = (float*)d_out;
    unsigned short* pre = (unsigned short*)d_ws;   // 2*6000*256*2 B = 6.1 MB

    embed_pre_kernel<<<dim3(2 * VBLK), dim3(256), 0, stream>>>(
        embed, Wk_f, b_f, Wk_b, b_b, pre);

    bilstm_mfma<<<dim3(256), dim3(512), 0, stream>>>(ids, Wr_f, Wr_b, pre, out);
}